// Round 2
// baseline (496.869 us; speedup 1.0000x reference)
//
#include <hip/hip_runtime.h>
#include <math.h>

// Problem constants (fixed by reference)
#define BS_TOT 32768      // B*S = 16*2048
#define IN_DIM 768
#define G_N 2
#define V_N 320
#define D_N 384
#define OUT_N 768
#define EPS_F 1e-10f

typedef _Float16 f16x8 __attribute__((ext_vector_type(8)));
typedef float    f32x16 __attribute__((ext_vector_type(16)));

#define GLOBAL_LOAD_LDS16(gaddr, laddr)                                        \
  __builtin_amdgcn_global_load_lds(                                            \
      (const __attribute__((address_space(1))) unsigned int*)(gaddr),          \
      (__attribute__((address_space(3))) unsigned int*)(laddr), 16, 0, 0)

// ---------------------------------------------------------------------------
// Kernel 0: split W_logits [384][320] fp32 into two f16 planes, laid out as
// five 96 KB column-chunk panels for ONE-TIME block staging:
//   panel c (cols 64c..64c+63), unit u = ((t*2+plane)*2+kh)*64 + col,
//   k = t*16 + kh*8 + j.  Plane 0 = f16(w); plane 1 = f16(4096*(w-plane0)).
// ---------------------------------------------------------------------------
__global__ __launch_bounds__(256) void prep_w(
    const float* __restrict__ Wl, _Float16* __restrict__ Wp)
{
    int e = blockIdx.x * 256 + threadIdx.x;
    if (e >= D_N * V_N) return;
    int k = e / V_N, v = e - k * V_N;
    int c = v >> 6, col = v & 63;
    int t = k >> 4, kh = (k >> 3) & 1, j = k & 7;
    float w = Wl[e];
    _Float16 a = (_Float16)w;
    float r = (w - (float)a) * 4096.f;
    size_t u0 = (size_t)c * 6144 + ((t * 2 + 0) * 2 + kh) * 64 + col;
    size_t u1 = (size_t)c * 6144 + ((t * 2 + 1) * 2 + kh) * 64 + col;
    Wp[u0 * 8 + j] = a;
    Wp[u1 * 8 + j] = (_Float16)r;
}

// ---------------------------------------------------------------------------
// Kernel A: P[g*320+v][o] = sum_d codebooks[g][v][d] * W_out[g*384+d][o]
// (unchanged — validated)
// ---------------------------------------------------------------------------
__global__ __launch_bounds__(256) void precompute_P(
    const float* __restrict__ cb, const float* __restrict__ Wo,
    float* __restrict__ P)
{
    const int tid = threadIdx.x;
    const int c0  = blockIdx.x * 256;
    const int r0  = blockIdx.y * 8;
    const int g   = r0 / V_N;
    __shared__ float As[8][D_N];
    {
        const float4* src = (const float4*)(cb + (size_t)r0 * D_N);
        float4* dst = (float4*)(&As[0][0]);
        #pragma unroll
        for (int p = 0; p < 3; ++p) dst[tid + p * 256] = src[tid + p * 256];
    }
    __syncthreads();
    float acc[8];
    #pragma unroll
    for (int i = 0; i < 8; ++i) acc[i] = 0.f;
    const float* wp = Wo + ((size_t)g * D_N) * OUT_N + c0 + tid;
    for (int d = 0; d < D_N; d += 4) {
        float w0 = wp[(size_t)(d + 0) * OUT_N];
        float w1 = wp[(size_t)(d + 1) * OUT_N];
        float w2 = wp[(size_t)(d + 2) * OUT_N];
        float w3 = wp[(size_t)(d + 3) * OUT_N];
        #pragma unroll
        for (int i = 0; i < 8; ++i) {
            float4 a = *(const float4*)&As[i][d];
            acc[i] = fmaf(a.x, w0, acc[i]);
            acc[i] = fmaf(a.y, w1, acc[i]);
            acc[i] = fmaf(a.z, w2, acc[i]);
            acc[i] = fmaf(a.w, w3, acc[i]);
        }
    }
    #pragma unroll
    for (int i = 0; i < 8; ++i)
        P[(size_t)(r0 + i) * OUT_N + c0 + tid] = acc[i];
}

// ---------------------------------------------------------------------------
// Kernel B1: B-stationary logits GEMM + gumbel + per-chunk argmax.
// Block = 256 rows x 64 cols x 1 group. B panel (96 KB, both f16 planes)
// staged ONCE via global_load_lds; after the single __syncthreads the K-loop
// has ZERO barriers and ZERO staging: per step each lane loads its own A
// fragment straight from z (8 consecutive floats = 2 dwordx4), converts to
// split-f16 in registers, ds_reads 4 B-frags, 12 MFMAs. z prefetched 3 steps
// deep in registers (static parity). Epilogue: bias+gumbel+argmax over the
// 64-col chunk -> (val,idx) partial per row.
// ---------------------------------------------------------------------------
__global__ __launch_bounds__(256, 1) void logits_part(
    const float* __restrict__ z, const float* __restrict__ noise,
    const f16x8* __restrict__ Wp, const float* __restrict__ bl,
    float* __restrict__ pv, int* __restrict__ pi)
{
    const int tid = threadIdx.x;
    const int ln  = tid & 63;
    const int wv  = tid >> 6;
    const int lh  = ln >> 5;
    const int l5  = ln & 31;
    const int cg  = blockIdx.x;        // 0..9
    const int cc  = cg % 5;            // N-chunk
    const int g   = cg / 5;            // group
    const int m0  = blockIdx.y * 256;  // 128 M-tiles

    __shared__ f16x8 Bs[6144];         // 98304 B: [(t*2+plane)*2+kh][64 cols]

    // ---- one-time B panel stage (24 gload_lds per thread) ------------------
    const f16x8* wsrc = Wp + (size_t)cc * 6144;
    #pragma unroll
    for (int r2 = 0; r2 < 24; ++r2)
        GLOBAL_LOAD_LDS16(wsrc + r2 * 256 + wv * 64 + ln, Bs + r2 * 256 + wv * 64);

    // ---- z prefetch: depth 3 (steps t, t+1, t+2) ---------------------------
    // lane's A addr: row = m0 + wv*64 + q*32 + l5, k = t*16 + lh*8 + {0..7}
    const float* zb = z + (size_t)(m0 + wv * 64 + l5) * IN_DIM + g * D_N + lh * 8;
    float4 bufA[4], bufB[4], bufC[4];
    #pragma unroll
    for (int q = 0; q < 2; ++q) {
        const float* zq = zb + (size_t)q * 32 * IN_DIM;
        bufA[q * 2]     = *(const float4*)(zq + 0);
        bufA[q * 2 + 1] = *(const float4*)(zq + 4);
        bufB[q * 2]     = *(const float4*)(zq + 16);
        bufB[q * 2 + 1] = *(const float4*)(zq + 20);
        bufC[q * 2]     = *(const float4*)(zq + 32);
        bufC[q * 2 + 1] = *(const float4*)(zq + 36);
    }

    f32x16 aM[2][2], aC[2][2];
    #pragma unroll
    for (int q = 0; q < 2; ++q)
        #pragma unroll
        for (int nf = 0; nf < 2; ++nf)
            #pragma unroll
            for (int i = 0; i < 16; ++i) { aM[q][nf][i] = 0.f; aC[q][nf][i] = 0.f; }

    __syncthreads();   // the ONLY block barrier: B panel resident

    // ---- K-loop: no barriers, no staging -----------------------------------
    auto step = [&](float4 (&buf)[4], int t) {
        f16x8 A0[2], A1[2];
        #pragma unroll
        for (int q = 0; q < 2; ++q) {
            float x[8] = {buf[q * 2].x, buf[q * 2].y, buf[q * 2].z, buf[q * 2].w,
                          buf[q * 2 + 1].x, buf[q * 2 + 1].y, buf[q * 2 + 1].z, buf[q * 2 + 1].w};
            f16x8 h1, h2;
            #pragma unroll
            for (int i = 0; i < 8; ++i) {
                _Float16 a = (_Float16)x[i];
                float r = (x[i] - (float)a) * 4096.f;
                h1[i] = a;
                h2[i] = (_Float16)r;
            }
            A0[q] = h1; A1[q] = h2;
        }
        if (t + 3 < 24) {   // refill consumed buffer 3 steps ahead
            #pragma unroll
            for (int q = 0; q < 2; ++q) {
                const float* zq = zb + (size_t)q * 32 * IN_DIM + (t + 3) * 16;
                buf[q * 2]     = *(const float4*)(zq);
                buf[q * 2 + 1] = *(const float4*)(zq + 4);
            }
        }
        #pragma unroll
        for (int nf = 0; nf < 2; ++nf) {
            f16x8 B0 = Bs[((t * 2 + 0) * 2 + lh) * 64 + nf * 32 + l5];
            f16x8 B1 = Bs[((t * 2 + 1) * 2 + lh) * 64 + nf * 32 + l5];
            #pragma unroll
            for (int q = 0; q < 2; ++q) {
                aM[q][nf] = __builtin_amdgcn_mfma_f32_32x32x16_f16(A0[q], B0, aM[q][nf], 0, 0, 0);
                aC[q][nf] = __builtin_amdgcn_mfma_f32_32x32x16_f16(A0[q], B1, aC[q][nf], 0, 0, 0);
                aC[q][nf] = __builtin_amdgcn_mfma_f32_32x32x16_f16(A1[q], B0, aC[q][nf], 0, 0, 0);
            }
        }
    };
    #pragma unroll
    for (int tt = 0; tt < 24; tt += 3) {
        step(bufA, tt);
        step(bufB, tt + 1);
        step(bufC, tt + 2);
    }

    // ---- epilogue: logits = main + 2^-12*cross + bl + gumbel; chunk argmax -
    float blv[2];
    #pragma unroll
    for (int nf = 0; nf < 2; ++nf) blv[nf] = bl[cc * 64 + nf * 32 + l5];

    #pragma unroll
    for (int q = 0; q < 2; ++q) {
        #pragma unroll
        for (int r = 0; r < 16; ++r) {
            const int rowloc = (r & 3) + 8 * (r >> 2) + 4 * lh;   // C/D row map
            const int grow   = m0 + wv * 64 + q * 32 + rowloc;
            const float* np_ = noise + ((size_t)grow * G_N + g) * V_N + cc * 64 + l5;
            float best = -INFINITY; int bi = 0;
            #pragma unroll
            for (int nf = 0; nf < 2; ++nf) {
                float u   = np_[nf * 32];
                float gum = -__logf(-__logf(u + EPS_F) + EPS_F);
                float v   = aM[q][nf][r] + 2.44140625e-4f * aC[q][nf][r] + blv[nf] + gum;
                int   c   = cc * 64 + nf * 32 + l5;               // global col
                if (v > best) { best = v; bi = c; }
            }
            #pragma unroll
            for (int off = 1; off < 32; off <<= 1) {   // reduce within 32-lane half
                float ov = __shfl_xor(best, off);
                int   oi = __shfl_xor(bi, off);
                if (ov > best || (ov == best && oi < bi)) { best = ov; bi = oi; }
            }
            if (l5 == 0) {
                pv[(size_t)(g * 5 + cc) * BS_TOT + grow] = best;
                pi[(size_t)(g * 5 + cc) * BS_TOT + grow] = bi;
            }
        }
    }
}

// ---------------------------------------------------------------------------
// Kernel B2: combine the 5 chunk-partials per (row, group) (strict > with
// ascending chunk == first-max == jnp.argmax semantics), then fused gather:
// out[row] = P[i0] + P[320+i1] + b_out.
// ---------------------------------------------------------------------------
__global__ __launch_bounds__(256) void finish_gather(
    const float* __restrict__ P, const float* __restrict__ pv,
    const int* __restrict__ pi, const float* __restrict__ bo,
    float* __restrict__ out)
{
    const int tid  = threadIdx.x;
    const int row0 = blockIdx.x << 2;
    __shared__ int sI[2][4];
    if (tid < 8) {
        const int gg  = tid >> 2, rl = tid & 3;
        const int row = row0 + rl;
        const float* pvb = pv + (size_t)gg * 5 * BS_TOT + row;
        const int*   pib = pi + (size_t)gg * 5 * BS_TOT + row;
        float best = pvb[0];
        int   bi   = pib[0];
        #pragma unroll
        for (int c = 1; c < 5; ++c) {
            float v = pvb[(size_t)c * BS_TOT];
            int   i = pib[(size_t)c * BS_TOT];
            if (v > best) { best = v; bi = i; }
        }
        sI[gg][rl] = bi;
    }
    __syncthreads();
    const float4* Pv  = (const float4*)P;
    const float4* bov = (const float4*)bo;
    #pragma unroll
    for (int p = 0; p < 3; ++p) {
        int f   = tid + (p << 8);
        int rl  = f / 192;
        int c4  = f - rl * 192;
        int i0  = sI[0][rl];
        int i1  = sI[1][rl];
        float4 a  = Pv[(size_t)i0 * 192 + c4];
        float4 b2 = Pv[(size_t)(V_N + i1) * 192 + c4];
        float4 c  = bov[c4];
        float4 r;
        r.x = a.x + b2.x + c.x;
        r.y = a.y + b2.y + c.y;
        r.z = a.z + b2.z + c.z;
        r.w = a.w + b2.w + c.w;
        ((float4*)(out + (size_t)(row0 + rl) * OUT_N))[c4] = r;
    }
}

// ---------------------------------------------------------------------------
extern "C" void kernel_launch(void* const* d_in, const int* in_sizes, int n_in,
                              void* d_out, int out_size, void* d_ws, size_t ws_size,
                              hipStream_t stream)
{
    const float* z     = (const float*)d_in[0];
    const float* noise = (const float*)d_in[1];
    const float* Wl    = (const float*)d_in[2];
    const float* bl    = (const float*)d_in[3];
    const float* cb    = (const float*)d_in[4];
    const float* Wo    = (const float*)d_in[5];
    const float* bo    = (const float*)d_in[6];
    float* out = (float*)d_out;

    // ws layout: P (1,966,080) | pv (1,310,720) | pi (1,310,720) | Wp (491,520)
    float*     P  = (float*)d_ws;
    float*     pv = (float*)((char*)d_ws + 1966080);
    int*       pi = (int*)((char*)d_ws + 3276800);
    _Float16*  Wp = (_Float16*)((char*)d_ws + 4587520);

    prep_w<<<(D_N * V_N + 255) / 256, 256, 0, stream>>>(Wl, Wp);

    dim3 gA(OUT_N / 256, (G_N * V_N) / 8);
    precompute_P<<<gA, 256, 0, stream>>>(cb, Wo, P);

    dim3 gB(10, BS_TOT / 256);   // x = (chunk,group) fastest -> same-M-tile
    logits_part<<<gB, 256, 0, stream>>>(z, noise, (const f16x8*)Wp, bl, pv, pi);

    finish_gather<<<BS_TOT / 4, 256, 0, stream>>>(P, pv, pi, bo, out);
}

// Round 4
// 368.095 us; speedup vs baseline: 1.3498x; 1.3498x over previous
//
#include <hip/hip_runtime.h>
#include <math.h>

// Problem constants (fixed by reference)
#define BS_TOT 32768      // B*S = 16*2048
#define IN_DIM 768
#define G_N 2
#define V_N 320
#define D_N 384
#define OUT_N 768
#define EPS_F 1e-10f

typedef _Float16 f16x8 __attribute__((ext_vector_type(8)));
typedef float    f32x16 __attribute__((ext_vector_type(16)));

#define GLOBAL_LOAD_LDS16(gaddr, laddr)                                        \
  __builtin_amdgcn_global_load_lds(                                            \
      (const __attribute__((address_space(1))) unsigned int*)(gaddr),          \
      (__attribute__((address_space(3))) unsigned int*)(laddr), 16, 0, 0)

// ---------------------------------------------------------------------------
// Kernel 0: split W_logits [384][320] fp32 into two f16 planes, laid out as
// five 96 KB column-chunk panels (validated R2 layout):
//   panel c (cols 64c..64c+63), unit u = ((t*2+plane)*2+kh)*64 + col,
//   k = t*16 + kh*8 + j.  Plane 0 = f16(w); plane 1 = f16(4096*(w-plane0)).
// Quarters (t in [6q,6q+6)) are contiguous 1536-unit ranges for ring staging.
// ---------------------------------------------------------------------------
__global__ __launch_bounds__(256) void prep_w(
    const float* __restrict__ Wl, _Float16* __restrict__ Wp)
{
    int e = blockIdx.x * 256 + threadIdx.x;
    if (e >= D_N * V_N) return;
    int k = e / V_N, v = e - k * V_N;
    int c = v >> 6, col = v & 63;
    int t = k >> 4, kh = (k >> 3) & 1, j = k & 7;
    float w = Wl[e];
    _Float16 a = (_Float16)w;
    float r = (w - (float)a) * 4096.f;
    size_t u0 = (size_t)c * 6144 + ((t * 2 + 0) * 2 + kh) * 64 + col;
    size_t u1 = (size_t)c * 6144 + ((t * 2 + 1) * 2 + kh) * 64 + col;
    Wp[u0 * 8 + j] = a;
    Wp[u1 * 8 + j] = (_Float16)r;
}

// ---------------------------------------------------------------------------
// Kernel A: P[g*320+v][o] = sum_d codebooks[g][v][d] * W_out[g*384+d][o]
// (unchanged — validated)
// ---------------------------------------------------------------------------
__global__ __launch_bounds__(256) void precompute_P(
    const float* __restrict__ cb, const float* __restrict__ Wo,
    float* __restrict__ P)
{
    const int tid = threadIdx.x;
    const int c0  = blockIdx.x * 256;
    const int r0  = blockIdx.y * 8;
    const int g   = r0 / V_N;
    __shared__ float As[8][D_N];
    {
        const float4* src = (const float4*)(cb + (size_t)r0 * D_N);
        float4* dst = (float4*)(&As[0][0]);
        #pragma unroll
        for (int p = 0; p < 3; ++p) dst[tid + p * 256] = src[tid + p * 256];
    }
    __syncthreads();
    float acc[8];
    #pragma unroll
    for (int i = 0; i < 8; ++i) acc[i] = 0.f;
    const float* wp = Wo + ((size_t)g * D_N) * OUT_N + c0 + tid;
    for (int d = 0; d < D_N; d += 4) {
        float w0 = wp[(size_t)(d + 0) * OUT_N];
        float w1 = wp[(size_t)(d + 1) * OUT_N];
        float w2 = wp[(size_t)(d + 2) * OUT_N];
        float w3 = wp[(size_t)(d + 3) * OUT_N];
        #pragma unroll
        for (int i = 0; i < 8; ++i) {
            float4 a = *(const float4*)&As[i][d];
            acc[i] = fmaf(a.x, w0, acc[i]);
            acc[i] = fmaf(a.y, w1, acc[i]);
            acc[i] = fmaf(a.z, w2, acc[i]);
            acc[i] = fmaf(a.w, w3, acc[i]);
        }
    }
    #pragma unroll
    for (int i = 0; i < 8; ++i)
        P[(size_t)(r0 + i) * OUT_N + c0 + tid] = acc[i];
}

// ---------------------------------------------------------------------------
// Kernel B1: logits GEMM + gumbel + per-chunk argmax.
// Block = 512 thr (8 waves) = 256 rows x 64 cols x 1 group; wave = 32x64.
// B panel streamed through a 48 KB LDS ring (2 slots x 6 K-steps), each
// quarter's global_load_lds issued 6 K-steps before the barrier that drains
// it. A is per-lane from z (8 consecutive floats), split-f16 in registers,
// depth-2 prefetch. 4 barriers total; acc = 64 VGPR -> launch_bounds(512,4)
// gives 2 blocks/CU = 4 waves/SIMD (R2's failure was 1 wave/SIMD).
// ---------------------------------------------------------------------------
__global__ __launch_bounds__(512, 4) void logits_part(
    const float* __restrict__ z, const float* __restrict__ noise,
    const f16x8* __restrict__ Wp, const float* __restrict__ bl,
    float* __restrict__ pv, int* __restrict__ pi)
{
    const int tid = threadIdx.x;
    const int ln  = tid & 63;
    const int wv  = tid >> 6;          // 0..7
    const int lh  = ln >> 5;
    const int l5  = ln & 31;
    const int cg  = blockIdx.x;        // 0..9
    const int cc  = cg % 5;            // N-chunk
    const int g   = cg / 5;            // group
    const int m0  = blockIdx.y * 256;  // M-tile base

    __shared__ f16x8 Bs[3072];         // 49152 B ring: 2 slots x 1536 units

    const f16x8* wsrc = Wp + (size_t)cc * 6144;

#define STAGEQ(Q, SLOT)                                                        \
    {                                                                          \
        _Pragma("unroll")                                                      \
        for (int i_ = 0; i_ < 3; ++i_)                                         \
            GLOBAL_LOAD_LDS16(wsrc + (Q) * 1536 + i_ * 512 + wv * 64 + ln,     \
                              Bs + (SLOT) * 1536 + i_ * 512 + wv * 64);        \
    }

    // prologue: stage Q0 -> slot0, Q1 -> slot1
    STAGEQ(0, 0)
    STAGEQ(1, 1)

    // z: lane's A fragment addr: row = m0 + wv*32 + l5, k = t*16 + lh*8 + j
    const float* zb = z + (size_t)(m0 + wv * 32 + l5) * IN_DIM + g * D_N + lh * 8;
    float4 pa0 = *(const float4*)(zb);        // t=0
    float4 pa1 = *(const float4*)(zb + 4);
    float4 pb0 = *(const float4*)(zb + 16);   // t=1
    float4 pb1 = *(const float4*)(zb + 20);

    f32x16 aM0, aM1, aC0, aC1;
    #pragma unroll
    for (int i = 0; i < 16; ++i) { aM0[i] = 0.f; aM1[i] = 0.f; aC0[i] = 0.f; aC1[i] = 0.f; }

    __syncthreads();   // Q0,Q1 resident

#define STEP(T, SLOT, P0, P1)                                                  \
    {                                                                          \
        float x_[8] = {P0.x, P0.y, P0.z, P0.w, P1.x, P1.y, P1.z, P1.w};        \
        f16x8 h1, h2;                                                          \
        _Pragma("unroll")                                                      \
        for (int i_ = 0; i_ < 8; ++i_) {                                       \
            _Float16 a_ = (_Float16)x_[i_];                                    \
            h1[i_] = a_;                                                       \
            h2[i_] = (_Float16)((x_[i_] - (float)a_) * 4096.f);                \
        }                                                                      \
        if ((T) + 2 < 24) {                                                    \
            P0 = *(const float4*)(zb + ((T) + 2) * 16);                        \
            P1 = *(const float4*)(zb + ((T) + 2) * 16 + 4);                    \
        }                                                                      \
        const int tq2_ = ((T) % 6) * 2;                                        \
        f16x8 Bm0 = Bs[(SLOT) * 1536 + ((tq2_ + 0) * 2 + lh) * 64 + l5];       \
        f16x8 Bc0 = Bs[(SLOT) * 1536 + ((tq2_ + 1) * 2 + lh) * 64 + l5];       \
        f16x8 Bm1 = Bs[(SLOT) * 1536 + ((tq2_ + 0) * 2 + lh) * 64 + 32 + l5];  \
        f16x8 Bc1 = Bs[(SLOT) * 1536 + ((tq2_ + 1) * 2 + lh) * 64 + 32 + l5];  \
        aM0 = __builtin_amdgcn_mfma_f32_32x32x16_f16(h1, Bm0, aM0, 0, 0, 0);   \
        aC0 = __builtin_amdgcn_mfma_f32_32x32x16_f16(h1, Bc0, aC0, 0, 0, 0);   \
        aC0 = __builtin_amdgcn_mfma_f32_32x32x16_f16(h2, Bm0, aC0, 0, 0, 0);   \
        aM1 = __builtin_amdgcn_mfma_f32_32x32x16_f16(h1, Bm1, aM1, 0, 0, 0);   \
        aC1 = __builtin_amdgcn_mfma_f32_32x32x16_f16(h1, Bc1, aC1, 0, 0, 0);   \
        aC1 = __builtin_amdgcn_mfma_f32_32x32x16_f16(h2, Bm1, aC1, 0, 0, 0);   \
    }

    STEP(0, 0, pa0, pa1) STEP(1, 0, pb0, pb1) STEP(2, 0, pa0, pa1)
    STEP(3, 0, pb0, pb1) STEP(4, 0, pa0, pa1) STEP(5, 0, pb0, pb1)
    __syncthreads();           // slot0 free (all waves past t=5)
    STAGEQ(2, 0)               // in flight across next 6 steps
    STEP(6, 1, pa0, pa1) STEP(7, 1, pb0, pb1) STEP(8, 1, pa0, pa1)
    STEP(9, 1, pb0, pb1) STEP(10, 1, pa0, pa1) STEP(11, 1, pb0, pb1)
    __syncthreads();           // drains Q2 DMA; slot1 free
    STAGEQ(3, 1)
    STEP(12, 0, pa0, pa1) STEP(13, 0, pb0, pb1) STEP(14, 0, pa0, pa1)
    STEP(15, 0, pb0, pb1) STEP(16, 0, pa0, pa1) STEP(17, 0, pb0, pb1)
    __syncthreads();           // drains Q3 DMA
    STEP(18, 1, pa0, pa1) STEP(19, 1, pb0, pb1) STEP(20, 1, pa0, pa1)
    STEP(21, 1, pb0, pb1) STEP(22, 1, pa0, pa1) STEP(23, 1, pb0, pb1)

#undef STEP
#undef STAGEQ

    // ---- epilogue: logits = main + 2^-12*cross + bl + gumbel; chunk argmax -
    const float blv0 = bl[cc * 64 + l5];
    const float blv1 = bl[cc * 64 + 32 + l5];
    const int   col0 = cc * 64 + l5;
    const int   col1 = cc * 64 + 32 + l5;

    #pragma unroll
    for (int r = 0; r < 16; ++r) {
        const int rowloc = (r & 3) + 8 * (r >> 2) + 4 * lh;   // C/D row map
        const int grow   = m0 + wv * 32 + rowloc;
        const float* np_ = noise + ((size_t)grow * G_N + g) * V_N + cc * 64 + l5;
        float u0 = np_[0];
        float u1 = np_[32];
        float g0 = -__logf(-__logf(u0 + EPS_F) + EPS_F);
        float g1 = -__logf(-__logf(u1 + EPS_F) + EPS_F);
        float v0 = aM0[r] + 2.44140625e-4f * aC0[r] + blv0 + g0;
        float v1 = aM1[r] + 2.44140625e-4f * aC1[r] + blv1 + g1;
        float best = v0; int bi = col0;
        if (v1 > best) { best = v1; bi = col1; }
        #pragma unroll
        for (int off = 1; off < 32; off <<= 1) {   // reduce within 32-lane half
            float ov = __shfl_xor(best, off);
            int   oi = __shfl_xor(bi, off);
            if (ov > best || (ov == best && oi < bi)) { best = ov; bi = oi; }
        }
        if (l5 == 0) {
            pv[(size_t)(g * 5 + cc) * BS_TOT + grow] = best;
            pi[(size_t)(g * 5 + cc) * BS_TOT + grow] = bi;
        }
    }
}

// ---------------------------------------------------------------------------
// Kernel B2: combine the 5 chunk-partials per (row, group) (strict > with
// ascending chunk == first-max == jnp.argmax semantics), then fused gather:
// out[row] = P[i0] + P[320+i1] + b_out. (unchanged — validated)
// ---------------------------------------------------------------------------
__global__ __launch_bounds__(256) void finish_gather(
    const float* __restrict__ P, const float* __restrict__ pv,
    const int* __restrict__ pi, const float* __restrict__ bo,
    float* __restrict__ out)
{
    const int tid  = threadIdx.x;
    const int row0 = blockIdx.x << 2;
    __shared__ int sI[2][4];
    if (tid < 8) {
        const int gg  = tid >> 2, rl = tid & 3;
        const int row = row0 + rl;
        const float* pvb = pv + (size_t)gg * 5 * BS_TOT + row;
        const int*   pib = pi + (size_t)gg * 5 * BS_TOT + row;
        float best = pvb[0];
        int   bi   = pib[0];
        #pragma unroll
        for (int c = 1; c < 5; ++c) {
            float v = pvb[(size_t)c * BS_TOT];
            int   i = pib[(size_t)c * BS_TOT];
            if (v > best) { best = v; bi = i; }
        }
        sI[gg][rl] = bi;
    }
    __syncthreads();
    const float4* Pv  = (const float4*)P;
    const float4* bov = (const float4*)bo;
    #pragma unroll
    for (int p = 0; p < 3; ++p) {
        int f   = tid + (p << 8);
        int rl  = f / 192;
        int c4  = f - rl * 192;
        int i0  = sI[0][rl];
        int i1  = sI[1][rl];
        float4 a  = Pv[(size_t)i0 * 192 + c4];
        float4 b2 = Pv[(size_t)(V_N + i1) * 192 + c4];
        float4 c  = bov[c4];
        float4 r;
        r.x = a.x + b2.x + c.x;
        r.y = a.y + b2.y + c.y;
        r.z = a.z + b2.z + c.z;
        r.w = a.w + b2.w + c.w;
        ((float4*)(out + (size_t)(row0 + rl) * OUT_N))[c4] = r;
    }
}

// ---------------------------------------------------------------------------
extern "C" void kernel_launch(void* const* d_in, const int* in_sizes, int n_in,
                              void* d_out, int out_size, void* d_ws, size_t ws_size,
                              hipStream_t stream)
{
    const float* z     = (const float*)d_in[0];
    const float* noise = (const float*)d_in[1];
    const float* Wl    = (const float*)d_in[2];
    const float* bl    = (const float*)d_in[3];
    const float* cb    = (const float*)d_in[4];
    const float* Wo    = (const float*)d_in[5];
    const float* bo    = (const float*)d_in[6];
    float* out = (float*)d_out;

    // ws layout: P (1,966,080) | pv (1,310,720) | pi (1,310,720) | Wp (491,520)
    float*     P  = (float*)d_ws;
    float*     pv = (float*)((char*)d_ws + 1966080);
    int*       pi = (int*)((char*)d_ws + 3276800);
    _Float16*  Wp = (_Float16*)((char*)d_ws + 4587520);

    prep_w<<<(D_N * V_N + 255) / 256, 256, 0, stream>>>(Wl, Wp);

    dim3 gA(OUT_N / 256, (G_N * V_N) / 8);
    precompute_P<<<gA, 256, 0, stream>>>(cb, Wo, P);

    dim3 gB(10, BS_TOT / 256);   // x = (chunk,group) fastest -> same-M-tile
    logits_part<<<gB, 512, 0, stream>>>(z, noise, (const f16x8*)Wp, bl, pv, pi);

    finish_gather<<<BS_TOT / 4, 256, 0, stream>>>(P, pv, pi, bo, out);
}